// Round 1
// baseline (5648.015 us; speedup 1.0000x reference)
//
#include <hip/hip_runtime.h>
#include <stdint.h>

// Problem constants (match reference)
#define N_NODES 50000
#define M_EDGES 25000
#define NNZF    800000
#define F_IN    128
#define HID     256
#define F_OUT   128

// ---------------- degree kernels ----------------
__global__ void count_deg(const int* __restrict__ nidx, const int* __restrict__ eidx,
                          float* __restrict__ cntN, float* __restrict__ cntE, int nnz) {
    int i = blockIdx.x * blockDim.x + threadIdx.x;
    if (i < nnz) {
        atomicAdd(cntN + nidx[i], 1.0f);
        atomicAdd(cntE + eidx[i], 1.0f);
    }
}

__global__ void invert_deg(float* __restrict__ a, int n) {
    int i = blockIdx.x * blockDim.x + threadIdx.x;
    if (i < n) { float v = a[i]; a[i] = (v > 0.f) ? 1.f / v : 0.f; }
}

// ---------------- scatter-add of 128-wide rows ----------------
// 32 threads per nnz entry, one float4 per thread.
template<bool SCALE_SRC>
__global__ void scatter_rows(const float* __restrict__ src,
                             const int* __restrict__ sidx, const int* __restrict__ didx,
                             const float* __restrict__ scale,
                             float* __restrict__ dst, int nnz) {
    int64_t t = (int64_t)blockIdx.x * blockDim.x + threadIdx.x;
    int k = (int)(t >> 5);
    if (k >= nnz) return;
    int f = (int)(t & 31) << 2;
    int s = sidx[k];
    int d = didx[k];
    float4 v = *reinterpret_cast<const float4*>(src + (int64_t)s * 128 + f);
    float sc = 1.0f;
    if (SCALE_SRC) sc = scale[s];
    float* p = dst + (int64_t)d * 128 + f;
    atomicAdd(p + 0, v.x * sc);
    atomicAdd(p + 1, v.y * sc);
    atomicAdd(p + 2, v.z * sc);
    atomicAdd(p + 3, v.w * sc);
}

// ---------------- elementwise row scale / finalize ----------------
__global__ void scale_rows(float* __restrict__ data, const float* __restrict__ scale, int rows) {
    int64_t t = (int64_t)blockIdx.x * blockDim.x + threadIdx.x;
    int r = (int)(t >> 5);
    if (r >= rows) return;
    int f = (int)(t & 31) << 2;
    float s = scale[r];
    float4* p = reinterpret_cast<float4*>(data + (int64_t)r * 128 + f);
    float4 v = *p;
    v.x *= s; v.y *= s; v.z *= s; v.w *= s;
    *p = v;
}

__global__ void finalize_out(float* __restrict__ out, const float* __restrict__ Dinv,
                             const float* __restrict__ b2, int rows) {
    int64_t t = (int64_t)blockIdx.x * blockDim.x + threadIdx.x;
    int r = (int)(t >> 5);
    if (r >= rows) return;
    int f = (int)(t & 31) << 2;
    float s = Dinv[r];
    float4 bv = *reinterpret_cast<const float4*>(b2 + f);
    float4* p = reinterpret_cast<float4*>(out + (int64_t)r * 128 + f);
    float4 v = *p;
    v.x = v.x * s + bv.x;
    v.y = v.y * s + bv.y;
    v.z = v.z * s + bv.z;
    v.w = v.w * s + bv.w;
    *p = v;
}

// ---------------- tiled fp32 GEMM: C[Mr,Nc] = act(scaleA?diag(rs):I * A[Mr,K] @ B[K,Nc] + bias) ----------------
template<bool SCALE_A, bool ELU, bool HAS_BIAS>
__global__ __launch_bounds__(256) void gemm_tiled(
    const float* __restrict__ A, const float* __restrict__ B,
    const float* __restrict__ bias, const float* __restrict__ rowscale,
    float* __restrict__ C, int Mr, int K, int Nc) {
    __shared__ float As[64][17];
    __shared__ float Bs[16][65];
    int tid = threadIdx.x;
    int tx = tid & 15, ty = tid >> 4;
    int rowBase = blockIdx.x * 64;
    int colBase = blockIdx.y * 64;

    int lr = tid >> 2, lc = (tid & 3) << 2;      // A tile load coords
    int br = tid >> 4, bc = (tid & 15) << 2;     // B tile load coords

    float c[4][4] = {};

    for (int k0 = 0; k0 < K; k0 += 16) {
        int ar = rowBase + lr;
        float4 av = make_float4(0.f, 0.f, 0.f, 0.f);
        if (ar < Mr) {
            av = *reinterpret_cast<const float4*>(A + (int64_t)ar * K + k0 + lc);
            if (SCALE_A) {
                float sc = rowscale[ar];
                av.x *= sc; av.y *= sc; av.z *= sc; av.w *= sc;
            }
        }
        As[lr][lc + 0] = av.x; As[lr][lc + 1] = av.y;
        As[lr][lc + 2] = av.z; As[lr][lc + 3] = av.w;

        float4 bv = *reinterpret_cast<const float4*>(B + (int64_t)(k0 + br) * Nc + colBase + bc);
        Bs[br][bc + 0] = bv.x; Bs[br][bc + 1] = bv.y;
        Bs[br][bc + 2] = bv.z; Bs[br][bc + 3] = bv.w;

        __syncthreads();
        #pragma unroll
        for (int kk = 0; kk < 16; ++kk) {
            float a0 = As[ty * 4 + 0][kk];
            float a1 = As[ty * 4 + 1][kk];
            float a2 = As[ty * 4 + 2][kk];
            float a3 = As[ty * 4 + 3][kk];
            float b0 = Bs[kk][tx * 4 + 0];
            float b1v = Bs[kk][tx * 4 + 1];
            float b2v = Bs[kk][tx * 4 + 2];
            float b3v = Bs[kk][tx * 4 + 3];
            c[0][0] += a0 * b0;  c[0][1] += a0 * b1v;  c[0][2] += a0 * b2v;  c[0][3] += a0 * b3v;
            c[1][0] += a1 * b0;  c[1][1] += a1 * b1v;  c[1][2] += a1 * b2v;  c[1][3] += a1 * b3v;
            c[2][0] += a2 * b0;  c[2][1] += a2 * b1v;  c[2][2] += a2 * b2v;  c[2][3] += a2 * b3v;
            c[3][0] += a3 * b0;  c[3][1] += a3 * b1v;  c[3][2] += a3 * b2v;  c[3][3] += a3 * b3v;
        }
        __syncthreads();
    }

    #pragma unroll
    for (int i = 0; i < 4; ++i) {
        int r = rowBase + ty * 4 + i;
        if (r >= Mr) continue;
        #pragma unroll
        for (int j = 0; j < 4; ++j) {
            int col = colBase + tx * 4 + j;
            float v = c[i][j];
            if (HAS_BIAS) v += bias[col];
            if (ELU) v = (v > 0.f) ? v : expm1f(v);
            C[(int64_t)r * Nc + col] = v;
        }
    }
}

// ---------------- launch ----------------
extern "C" void kernel_launch(void* const* d_in, const int* in_sizes, int n_in,
                              void* d_out, int out_size, void* d_ws, size_t ws_size,
                              hipStream_t stream) {
    const float* x   = (const float*)d_in[0];
    const float* W1  = (const float*)d_in[1];
    const float* b1  = (const float*)d_in[2];
    const float* W2  = (const float*)d_in[3];
    const float* b2  = (const float*)d_in[4];
    const int*   nidx = (const int*)d_in[5];
    const int*   eidx = (const int*)d_in[6];

    float* out   = (float*)d_out;                              // [N, 128]
    float* e_out = out + (size_t)N_NODES * F_OUT;              // [M, 128]

    char* ws = (char*)d_ws;
    size_t off = 0;
    auto alloc = [&](size_t bytes) -> void* {
        void* p = ws + off;
        off += (bytes + 511) & ~(size_t)511;
        return p;
    };
    float* Dinv = (float*)alloc((size_t)N_NODES * 4);
    float* Binv = (float*)alloc((size_t)M_EDGES * 4);
    float* y    = (float*)alloc((size_t)M_EDGES * F_IN * 4);   // edge accum, 128 wide
    float* z    = (float*)alloc((size_t)N_NODES * F_IN * 4);   // node accum; reused as hp
    float* h    = (float*)alloc((size_t)N_NODES * HID * 4);    // hidden [N,256]

    hipMemsetAsync(Dinv, 0, (size_t)N_NODES * 4, stream);
    hipMemsetAsync(Binv, 0, (size_t)M_EDGES * 4, stream);
    hipMemsetAsync(y,    0, (size_t)M_EDGES * F_IN * 4, stream);
    hipMemsetAsync(z,    0, (size_t)N_NODES * F_IN * 4, stream);
    hipMemsetAsync(d_out, 0, (size_t)out_size * 4, stream);

    // degrees
    count_deg<<<(NNZF + 255) / 256, 256, 0, stream>>>(nidx, eidx, Dinv, Binv, NNZF);
    invert_deg<<<(N_NODES + 255) / 256, 256, 0, stream>>>(Dinv, N_NODES);
    invert_deg<<<(M_EDGES + 255) / 256, 256, 0, stream>>>(Binv, M_EDGES);

    int64_t sthreads = (int64_t)NNZF * 32;
    int sblocks = (int)((sthreads + 255) / 256);

    // y = S^T x  (node -> edge, raw sum)
    scatter_rows<false><<<sblocks, 256, 0, stream>>>(x, nidx, eidx, nullptr, y, NNZF);
    // z = S (Binv .* y)  (edge -> node)
    scatter_rows<true><<<sblocks, 256, 0, stream>>>(y, eidx, nidx, Binv, z, NNZF);

    // h = elu( (Dinv .* z) @ W1 + b1 )   [N,256]
    dim3 g1((N_NODES + 63) / 64, HID / 64);
    gemm_tiled<true, true, true><<<g1, 256, 0, stream>>>(z, W1, b1, Dinv, h, N_NODES, F_IN, HID);

    // hp = h @ W2   [N,128]  (reuse z buffer)
    dim3 g2((N_NODES + 63) / 64, F_OUT / 64);
    gemm_tiled<false, false, false><<<g2, 256, 0, stream>>>(h, W2, nullptr, nullptr, z, N_NODES, HID, F_OUT);

    // e_raw = S^T hp  (node -> edge), directly into output slot
    scatter_rows<false><<<sblocks, 256, 0, stream>>>(z, nidx, eidx, nullptr, e_out, NNZF);
    // e = Binv .* e_raw
    scale_rows<<<(int)(((int64_t)M_EDGES * 32 + 255) / 256), 256, 0, stream>>>(e_out, Binv, M_EDGES);

    // out_raw = S e  (edge -> node)
    scatter_rows<false><<<sblocks, 256, 0, stream>>>(e_out, eidx, nidx, nullptr, out, NNZF);
    // out = Dinv .* out_raw + b2
    finalize_out<<<(int)(((int64_t)N_NODES * 32 + 255) / 256), 256, 0, stream>>>(out, Dinv, b2, N_NODES);
}

// Round 2
// 649.433 us; speedup vs baseline: 8.6968x; 8.6968x over previous
//
#include <hip/hip_runtime.h>
#include <stdint.h>

#define N_NODES 50000
#define M_EDGES 25000
#define NNZF    800000
#define F_IN    128
#define HID     256
#define F_OUT   128

// ---------------- histogram (int counts) ----------------
__global__ void hist_deg(const int* __restrict__ nidx, const int* __restrict__ eidx,
                         int* __restrict__ cntN, int* __restrict__ cntE, int nnz) {
    int i = blockIdx.x * blockDim.x + threadIdx.x;
    if (i < nnz) {
        atomicAdd(cntN + nidx[i], 1);
        atomicAdd(cntE + eidx[i], 1);
    }
}

__global__ void inv_from_cnt(const int* __restrict__ cnt, float* __restrict__ inv, int n) {
    int i = blockIdx.x * blockDim.x + threadIdx.x;
    if (i < n) { int v = cnt[i]; inv[i] = (v > 0) ? 1.0f / (float)v : 0.0f; }
}

// ---------------- one-block exclusive scan (n up to ~64K) ----------------
__global__ __launch_bounds__(256) void excl_scan(const int* __restrict__ cnt,
                                                 int* __restrict__ starts, int n) {
    __shared__ int part[256];
    __shared__ int partx[257];
    int tid = threadIdx.x;
    int chunk = (n + 255) / 256;
    int lo = tid * chunk;
    int hi = lo + chunk; if (hi > n) hi = n;
    int s = 0;
    for (int i = lo; i < hi; ++i) s += cnt[i];
    part[tid] = s;
    __syncthreads();
    if (tid == 0) {
        int run = 0;
        for (int i = 0; i < 256; ++i) { partx[i] = run; run += part[i]; }
        partx[256] = run;
    }
    __syncthreads();
    int run = partx[tid];
    for (int i = lo; i < hi; ++i) { starts[i] = run; run += cnt[i]; }
    if (hi == n && lo < n) starts[n] = run;
    if (n == 0 && tid == 0) starts[0] = 0;
}

// ---------------- CSR fill ----------------
__global__ void fill_csr(const int* __restrict__ nidx, const int* __restrict__ eidx,
                         const int* __restrict__ startN, const int* __restrict__ startE,
                         int* __restrict__ curN, int* __restrict__ curE,
                         int* __restrict__ listN, int* __restrict__ listE, int nnz) {
    int i = blockIdx.x * blockDim.x + threadIdx.x;
    if (i < nnz) {
        int nd = nidx[i], ed = eidx[i];
        int pe = startE[ed] + atomicAdd(curE + ed, 1);
        listE[pe] = nd;                       // sources (nodes) grouped by edge
        int pn = startN[nd] + atomicAdd(curN + nd, 1);
        listN[pn] = ed;                       // sources (edges) grouped by node
    }
}

// ---------------- gather segment-sum of 128-wide rows ----------------
// one wave (64 lanes) per destination row; lane handles float2 (features 2*lane, 2*lane+1)
template<bool SCALE_DST, bool ADD_BIAS>
__global__ __launch_bounds__(256) void gather_rows(
    const float* __restrict__ src, const int* __restrict__ starts,
    const int* __restrict__ list, const float* __restrict__ dstscale,
    const float* __restrict__ bias, float* __restrict__ dst, int rows) {
    int row = blockIdx.x * 4 + (threadIdx.x >> 6);
    if (row >= rows) return;
    int lane = threadIdx.x & 63;
    int s0 = starts[row], s1 = starts[row + 1];
    float ax = 0.f, ay = 0.f;
    int j = s0;
    for (; j + 4 <= s1; j += 4) {
        int i0 = list[j + 0], i1 = list[j + 1], i2 = list[j + 2], i3 = list[j + 3];
        float2 v0 = *reinterpret_cast<const float2*>(src + (int64_t)i0 * 128 + lane * 2);
        float2 v1 = *reinterpret_cast<const float2*>(src + (int64_t)i1 * 128 + lane * 2);
        float2 v2 = *reinterpret_cast<const float2*>(src + (int64_t)i2 * 128 + lane * 2);
        float2 v3 = *reinterpret_cast<const float2*>(src + (int64_t)i3 * 128 + lane * 2);
        ax += v0.x + v1.x + v2.x + v3.x;
        ay += v0.y + v1.y + v2.y + v3.y;
    }
    for (; j < s1; ++j) {
        int i0 = list[j];
        float2 v0 = *reinterpret_cast<const float2*>(src + (int64_t)i0 * 128 + lane * 2);
        ax += v0.x; ay += v0.y;
    }
    if (SCALE_DST) { float sc = dstscale[row]; ax *= sc; ay *= sc; }
    if (ADD_BIAS)  { ax += bias[lane * 2]; ay += bias[lane * 2 + 1]; }
    float2 o; o.x = ax; o.y = ay;
    *reinterpret_cast<float2*>(dst + (int64_t)row * 128 + lane * 2) = o;
}

// ---------------- tiled fp32 GEMM ----------------
template<bool SCALE_A, bool ELU, bool HAS_BIAS>
__global__ __launch_bounds__(256) void gemm_tiled(
    const float* __restrict__ A, const float* __restrict__ B,
    const float* __restrict__ bias, const float* __restrict__ rowscale,
    float* __restrict__ C, int Mr, int K, int Nc) {
    __shared__ float As[64][17];
    __shared__ float Bs[16][65];
    int tid = threadIdx.x;
    int tx = tid & 15, ty = tid >> 4;
    int rowBase = blockIdx.x * 64;
    int colBase = blockIdx.y * 64;

    int lr = tid >> 2, lc = (tid & 3) << 2;
    int br = tid >> 4, bc = (tid & 15) << 2;

    float c[4][4] = {};

    for (int k0 = 0; k0 < K; k0 += 16) {
        int ar = rowBase + lr;
        float4 av = make_float4(0.f, 0.f, 0.f, 0.f);
        if (ar < Mr) {
            av = *reinterpret_cast<const float4*>(A + (int64_t)ar * K + k0 + lc);
            if (SCALE_A) {
                float sc = rowscale[ar];
                av.x *= sc; av.y *= sc; av.z *= sc; av.w *= sc;
            }
        }
        As[lr][lc + 0] = av.x; As[lr][lc + 1] = av.y;
        As[lr][lc + 2] = av.z; As[lr][lc + 3] = av.w;

        float4 bv = *reinterpret_cast<const float4*>(B + (int64_t)(k0 + br) * Nc + colBase + bc);
        Bs[br][bc + 0] = bv.x; Bs[br][bc + 1] = bv.y;
        Bs[br][bc + 2] = bv.z; Bs[br][bc + 3] = bv.w;

        __syncthreads();
        #pragma unroll
        for (int kk = 0; kk < 16; ++kk) {
            float a0 = As[ty * 4 + 0][kk];
            float a1 = As[ty * 4 + 1][kk];
            float a2 = As[ty * 4 + 2][kk];
            float a3 = As[ty * 4 + 3][kk];
            float b0 = Bs[kk][tx * 4 + 0];
            float b1v = Bs[kk][tx * 4 + 1];
            float b2v = Bs[kk][tx * 4 + 2];
            float b3v = Bs[kk][tx * 4 + 3];
            c[0][0] += a0 * b0;  c[0][1] += a0 * b1v;  c[0][2] += a0 * b2v;  c[0][3] += a0 * b3v;
            c[1][0] += a1 * b0;  c[1][1] += a1 * b1v;  c[1][2] += a1 * b2v;  c[1][3] += a1 * b3v;
            c[2][0] += a2 * b0;  c[2][1] += a2 * b1v;  c[2][2] += a2 * b2v;  c[2][3] += a2 * b3v;
            c[3][0] += a3 * b0;  c[3][1] += a3 * b1v;  c[3][2] += a3 * b2v;  c[3][3] += a3 * b3v;
        }
        __syncthreads();
    }

    #pragma unroll
    for (int i = 0; i < 4; ++i) {
        int r = rowBase + ty * 4 + i;
        if (r >= Mr) continue;
        #pragma unroll
        for (int j = 0; j < 4; ++j) {
            int col = colBase + tx * 4 + j;
            float v = c[i][j];
            if (HAS_BIAS) v += bias[col];
            if (ELU) v = (v > 0.f) ? v : expm1f(v);
            C[(int64_t)r * Nc + col] = v;
        }
    }
}

// ---------------- launch ----------------
extern "C" void kernel_launch(void* const* d_in, const int* in_sizes, int n_in,
                              void* d_out, int out_size, void* d_ws, size_t ws_size,
                              hipStream_t stream) {
    const float* x   = (const float*)d_in[0];
    const float* W1  = (const float*)d_in[1];
    const float* b1  = (const float*)d_in[2];
    const float* W2  = (const float*)d_in[3];
    const float* b2  = (const float*)d_in[4];
    const int*   nidx = (const int*)d_in[5];
    const int*   eidx = (const int*)d_in[6];

    float* out   = (float*)d_out;                      // [N, 128]
    float* e_out = out + (size_t)N_NODES * F_OUT;      // [M, 128]

    char* ws = (char*)d_ws;
    size_t off = 0;
    auto alloc = [&](size_t bytes) -> void* {
        void* p = ws + off;
        off += (bytes + 511) & ~(size_t)511;
        return p;
    };
    float* Dinv  = (float*)alloc((size_t)N_NODES * 4);
    float* Binv  = (float*)alloc((size_t)M_EDGES * 4);
    int* cntN    = (int*)alloc((size_t)N_NODES * 4);
    int* cntE    = (int*)alloc((size_t)M_EDGES * 4);
    int* startN  = (int*)alloc((size_t)(N_NODES + 1) * 4);
    int* startE  = (int*)alloc((size_t)(M_EDGES + 1) * 4);
    int* curN    = (int*)alloc((size_t)N_NODES * 4);
    int* curE    = (int*)alloc((size_t)M_EDGES * 4);
    int* listN   = (int*)alloc((size_t)NNZF * 4);      // edges grouped by node
    int* listE   = (int*)alloc((size_t)NNZF * 4);      // nodes grouped by edge
    float* y     = (float*)alloc((size_t)M_EDGES * F_IN * 4);   // [M,128]
    float* z     = (float*)alloc((size_t)N_NODES * F_IN * 4);   // [N,128]; reused for hp
    float* h     = (float*)alloc((size_t)N_NODES * HID * 4);    // [N,256]

    hipMemsetAsync(cntN, 0, (size_t)N_NODES * 4, stream);
    hipMemsetAsync(cntE, 0, (size_t)M_EDGES * 4, stream);
    hipMemsetAsync(curN, 0, (size_t)N_NODES * 4, stream);
    hipMemsetAsync(curE, 0, (size_t)M_EDGES * 4, stream);

    // degrees + CSR
    hist_deg<<<(NNZF + 255) / 256, 256, 0, stream>>>(nidx, eidx, cntN, cntE, NNZF);
    inv_from_cnt<<<(N_NODES + 255) / 256, 256, 0, stream>>>(cntN, Dinv, N_NODES);
    inv_from_cnt<<<(M_EDGES + 255) / 256, 256, 0, stream>>>(cntE, Binv, M_EDGES);
    excl_scan<<<1, 256, 0, stream>>>(cntN, startN, N_NODES);
    excl_scan<<<1, 256, 0, stream>>>(cntE, startE, M_EDGES);
    fill_csr<<<(NNZF + 255) / 256, 256, 0, stream>>>(nidx, eidx, startN, startE,
                                                     curN, curE, listN, listE, NNZF);

    // layer 1 propagation (feature width 128, pre-GEMM)
    // y = Binv .* (S^T x)
    gather_rows<true, false><<<(M_EDGES + 3) / 4, 256, 0, stream>>>(
        x, startE, listE, Binv, nullptr, y, M_EDGES);
    // z = S y
    gather_rows<false, false><<<(N_NODES + 3) / 4, 256, 0, stream>>>(
        y, startN, listN, nullptr, nullptr, z, N_NODES);

    // h = elu( (Dinv .* z) @ W1 + b1 )   [N,256]
    dim3 g1((N_NODES + 63) / 64, HID / 64);
    gemm_tiled<true, true, true><<<g1, 256, 0, stream>>>(z, W1, b1, Dinv, h, N_NODES, F_IN, HID);

    // hp = h @ W2  [N,128]  (into z)
    dim3 g2((N_NODES + 63) / 64, F_OUT / 64);
    gemm_tiled<false, false, false><<<g2, 256, 0, stream>>>(h, W2, nullptr, nullptr, z, N_NODES, HID, F_OUT);

    // e = Binv .* (S^T hp)  -> output slot
    gather_rows<true, false><<<(M_EDGES + 3) / 4, 256, 0, stream>>>(
        z, startE, listE, Binv, nullptr, e_out, M_EDGES);
    // out = Dinv .* (S e) + b2
    gather_rows<true, true><<<(N_NODES + 3) / 4, 256, 0, stream>>>(
        e_out, startN, listN, Dinv, b2, out, N_NODES);
}